// Round 14
// baseline (173.733 us; speedup 1.0000x reference)
//
#include <hip/hip_runtime.h>

#define NSRC 50000
#define NDST 10000
#define NEDGE 250000
#define NREL 4
#define NEG_SLOPE 0.2f
#define EMAXC 128  // cached alphas per (d,r) segment; degree Binomial(250k,1e-4), max ~55
#define NSEG (NREL * NDST)
#define NBLK 32        // CSR-build blocks per relation
#define CHUNK 7813     // ceil(NEDGE / NBLK); fits u16 rank

typedef unsigned short u16;
typedef __attribute__((ext_vector_type(8))) short bf16x8;
typedef __attribute__((ext_vector_type(4))) float f32x4;
typedef __attribute__((ext_vector_type(2))) float f32x2;

#define GLD16(g, l) __builtin_amdgcn_global_load_lds( \
    (__attribute__((address_space(1))) void*)(void*)(g), \
    (__attribute__((address_space(3))) void*)(l), 16, 0, 0)

static __device__ __forceinline__ u16 f2b(float f) {
  unsigned u = __float_as_uint(f);
  unsigned r = (u + 0x7FFFu + ((u >> 16) & 1u)) >> 16;
  return (u16)r;
}
static __device__ __forceinline__ float b2f(u16 b) {
  return __uint_as_float((unsigned)b << 16);
}
static __device__ __forceinline__ float leaky(float x) {
  return x > 0.f ? x : NEG_SLOPE * x;
}

// ---------- fp8 e4m3 (OCP) helpers ----------
static __device__ __forceinline__ unsigned enc8_sw(float f) {
  unsigned s = (__float_as_uint(f) >> 24) & 0x80u;
  float a = fminf(fabsf(f), 448.f);
  unsigned em;
  if (a < 0x1p-6f) {
    em = (unsigned)rintf(a * 512.f);  // subnormal (and exact 2^-6 boundary)
  } else {
    unsigned ab = __float_as_uint(a);
    unsigned lsb = (ab >> 20) & 1u;
    ab += 0x7FFFFu + lsb;             // RNE to 3 mantissa bits
    int e = (int)(ab >> 23) - 127;
    unsigned m = (ab >> 20) & 7u;
    em = (unsigned)((e + 7) << 3) | m;
    if (em > 0x7Eu) em = 0x7Eu;       // clamp to 448
  }
  return s | em;
}
static __device__ __forceinline__ float dec8_sw(unsigned b) {
  unsigned s = b & 0x80u;
  unsigned em = b & 0x7Fu;
  float n = __uint_as_float((s << 24) | ((em << 20) + 0x3C000000u));
  float sub = (s ? -1.f : 1.f) * (float)em * 0x1p-9f;
  return em >= 8 ? n : sub;
}
static __device__ __forceinline__ unsigned enc4(float a, float b, float c, float d) {
#if __has_builtin(__builtin_amdgcn_cvt_pk_fp8_f32)
  int q = __builtin_amdgcn_cvt_pk_fp8_f32(a, b, 0, 0);
  q = __builtin_amdgcn_cvt_pk_fp8_f32(c, d, q, 1);
  return (unsigned)q;
#else
  return enc8_sw(a) | (enc8_sw(b) << 8) | (enc8_sw(c) << 16) | (enc8_sw(d) << 24);
#endif
}
static __device__ __forceinline__ void dec4(unsigned q, float f[4]) {
#if __has_builtin(__builtin_amdgcn_cvt_pk_f32_fp8)
  f32x2 lo = __builtin_amdgcn_cvt_pk_f32_fp8((int)q, 0);
  f32x2 hi = __builtin_amdgcn_cvt_pk_f32_fp8((int)q, 1);
  f[0] = lo.x; f[1] = lo.y; f[2] = hi.x; f[3] = hi.y;
#else
  f[0] = dec8_sw(q & 0xff); f[1] = dec8_sw((q >> 8) & 0xff);
  f[2] = dec8_sw((q >> 16) & 0xff); f[3] = dec8_sw(q >> 24);
#endif
}
// pack 2 f32 -> 1 u32 of 2 bf16 (exact here: inputs are fp8-valued)
static __device__ __forceinline__ unsigned pk_bf16(float a, float b) {
  unsigned r;
  asm("v_cvt_pk_bf16_f32 %0, %1, %2" : "=v"(r) : "v"(a), "v"(b));
  return r;
}
// 8 fp8 (2 u32) -> 8 bf16 (uint4)
static __device__ __forceinline__ uint4 dec8_bf16(unsigned q0, unsigned q1) {
  float f[8];
  dec4(q0, f);
  dec4(q1, f + 4);
  uint4 o;
  o.x = pk_bf16(f[0], f[1]);
  o.y = pk_bf16(f[2], f[3]);
  o.z = pk_bf16(f[4], f[5]);
  o.w = pk_bf16(f[6], f[7]);
  return o;
}

// ---------------- merged prep (no hist): cvtx(+fp8) | cvtwBL | wa ----------------
#define CB_CVTX 1563
#define CB_WBL  160
#define CB_WA   16
#define NGRP 3200000       // NSRC*256/4 float4-groups

__global__ __launch_bounds__(256) void prep_k(const float* __restrict__ x,
                                              const float* __restrict__ W,
                                              const float* __restrict__ loop_w,
                                              const float* __restrict__ al,
                                              const float* __restrict__ ar,
                                              u16* __restrict__ xb,
                                              unsigned* __restrict__ xq,
                                              u16* __restrict__ WBL,
                                              u16* __restrict__ WAt) {
  const int bi = blockIdx.x;
  const int tid = threadIdx.x;
  if (bi < CB_CVTX) {
    const int base = bi * 2048 + tid;
    float4 v[8];
    #pragma unroll
    for (int it = 0; it < 8; ++it) {
      int i = base + it * 256;
      if (i < NGRP) v[it] = ((const float4*)x)[i];
    }
    #pragma unroll
    for (int it = 0; it < 8; ++it) {
      int i = base + it * 256;
      if (i < NGRP) {
        uint2 o;
        o.x = (unsigned)f2b(v[it].x) | ((unsigned)f2b(v[it].y) << 16);
        o.y = (unsigned)f2b(v[it].z) | ((unsigned)f2b(v[it].w) << 16);
        ((uint2*)xb)[i] = o;
        xq[i] = enc4(v[it].x, v[it].y, v[it].z, v[it].w);
      }
    }
  } else if (bi < CB_CVTX + CB_WBL) {
    // WBL[h][n(64)][k'(1280)]: k'<1024 -> 0.25*W[k'>>8][k'&255][h*64+n]; else loop_w
    const int g0 = (bi - CB_CVTX) * 2048 + tid;
    float v[8];
    #pragma unroll
    for (int it = 0; it < 8; ++it) {
      int g = g0 + it * 256;  // g < 327680 always (exact fit)
      int h = g / 81920, rem = g - h * 81920;
      int np = rem / 1280, kp = rem - np * 1280;
      if (kp < 1024)
        v[it] = 0.25f * W[(size_t)(kp >> 8) * 65536 + (size_t)(kp & 255) * 256 + h * 64 + np];
      else
        v[it] = loop_w[(size_t)(kp - 1024) * 256 + h * 64 + np];
    }
    #pragma unroll
    for (int it = 0; it < 8; ++it) WBL[g0 + it * 256] = f2b(v[it]);
  } else {
    const int g0 = (bi - CB_CVTX - CB_WBL) * 2048 + tid;
    #pragma unroll
    for (int it = 0; it < 8; ++it) {
      int g = g0 + it * 256;  // g < 32768 always
      int c = g >> 8, k = g & 255;
      float acc = 0.f;
      if (c < 32) {
        int cc = c & 15;
        int r = cc >> 2, h = cc & 3;
        const float* vec = ((c < 16) ? al : ar) + r * 256 + h * 64;
        const float* wrow = W + (size_t)r * 65536 + (size_t)k * 256 + h * 64;
        #pragma unroll 8
        for (int j = 0; j < 64; ++j) acc += wrow[j] * vec[j];
      }
      WAt[(size_t)c * 256 + k] = f2b(acc);
    }
  }
}

// ---------------- atomic-free CSR build ----------------
__global__ __launch_bounds__(256) void histrank_k(const int* __restrict__ edst,
                                                  u16* __restrict__ ranks,
                                                  unsigned* __restrict__ bhist) {
  __shared__ unsigned lh[NDST];  // 40 KB
  const int bi = blockIdx.x, r = blockIdx.y;
  for (int i = threadIdx.x; i < NDST; i += 256) lh[i] = 0;
  __syncthreads();
  const int base = bi * CHUNK;
  const int lim = (NEDGE - base < CHUNK) ? (NEDGE - base) : CHUNK;
  const int* ed = edst + (size_t)r * NEDGE + base;
  u16* rk = ranks + (size_t)r * NEDGE + base;
  for (int i = threadIdx.x; i < lim; i += 256) {
    int d = ed[i];
    rk[i] = (u16)atomicAdd(&lh[d], 1u);
  }
  __syncthreads();
  unsigned* bh = bhist + ((size_t)r * NBLK + bi) * NDST;
  for (int i = threadIdx.x; i < NDST; i += 256) bh[i] = lh[i];
}

__global__ __launch_bounds__(256) void scanbb_k(unsigned* __restrict__ bhist,
                                                int* __restrict__ counts) {
  int gid = blockIdx.x * 256 + threadIdx.x;
  if (gid >= NSEG) return;
  int r = gid / NDST, bin = gid - r * NDST;
  unsigned run = 0;
  unsigned* base = bhist + (size_t)r * NBLK * NDST + bin;
  #pragma unroll
  for (int b = 0; b < NBLK; ++b) {
    unsigned v = base[(size_t)b * NDST];
    base[(size_t)b * NDST] = run;
    run += v;
  }
  counts[gid] = (int)run;
}

__global__ void place_k(const int* __restrict__ esrc, const int* __restrict__ edst,
                        const u16* __restrict__ ranks,
                        const unsigned* __restrict__ bhist,
                        const int* __restrict__ offs, int* __restrict__ perm) {
  int g = blockIdx.x * 256 + threadIdx.x;
  if (g >= NREL * NEDGE) return;
  int r = g / NEDGE, e = g - r * NEDGE;
  int bi = e / CHUNK;
  int d = edst[g];
  int pos = offs[r * NDST + d] +
            (int)bhist[((size_t)r * NBLK + bi) * NDST + d] + (int)ranks[g];
  perm[pos] = esrc[g];
}

// ---------------- seg-offset scans (coalesced, 3 kernels) ----------------
__global__ __launch_bounds__(1024) void scanA_k(const int* __restrict__ counts,
                                                int* __restrict__ offsets,
                                                int* __restrict__ btot) {
  __shared__ int wsum[16];
  int tid = threadIdx.x, lane = tid & 63, wid = tid >> 6;
  int i = blockIdx.x * 1024 + tid;
  int v = (i < NSEG) ? counts[i] : 0;
  int x = v;
  #pragma unroll
  for (int off = 1; off < 64; off <<= 1) {
    int t = __shfl_up(x, off);
    if (lane >= off) x += t;
  }
  if (lane == 63) wsum[wid] = x;
  __syncthreads();
  if (wid == 0) {
    int t = (lane < 16) ? wsum[lane] : 0;
    #pragma unroll
    for (int off = 1; off < 16; off <<= 1) {
      int u = __shfl_up(t, off);
      if (lane >= off) t += u;
    }
    if (lane < 16) wsum[lane] = t;
  }
  __syncthreads();
  int wpre = (wid > 0) ? wsum[wid - 1] : 0;
  int incl = x + wpre;
  if (i < NSEG) offsets[i] = incl - v;
  if (tid == 1023) btot[blockIdx.x] = incl;
}

__global__ void scanB_k(const int* __restrict__ btot, int* __restrict__ carry) {
  int lane = threadIdx.x;  // 64 threads = 1 wave
  int v = (lane < 40) ? btot[lane] : 0;
  int x = v;
  #pragma unroll
  for (int off = 1; off < 64; off <<= 1) {
    int t = __shfl_up(x, off);
    if (lane >= off) x += t;
  }
  if (lane < 40) carry[lane] = x - v;
}

__global__ __launch_bounds__(1024) void scanC_k(int* __restrict__ offsets,
                                                const int* __restrict__ carry) {
  int i = blockIdx.x * 1024 + threadIdx.x;
  if (i < NSEG) offsets[i] += carry[blockIdx.x];
  if (i == 0) offsets[NSEG] = NREL * NEDGE;
}

// ---------------- elr GEMM: elr[NSRC][32] = xb @ WAt^T (N=32 tile) ----------------
__global__ __launch_bounds__(256) void gemmE_k(const u16* __restrict__ A,
                                               const u16* __restrict__ B,
                                               float* __restrict__ outF) {
  __shared__ u16 As[128 * 64];
  __shared__ u16 Bs[32 * 64];
  const int tid = threadIdx.x;
  const int w = tid >> 6, l = tid & 63;
  const int bm = blockIdx.y * 128;
  const int wm = w * 32;
  f32x4 acc[2][2] = {};
  const int lrow = l >> 3, lchunk = l & 7;

  for (int t = 0; t < 4; ++t) {
    const int k0 = t * 64;
    #pragma unroll
    for (int c = 0; c < 4; ++c) {
      int rb = (w * 4 + c) * 8;
      int row_in = rb + lrow;
      int colb = (lchunk * 16) ^ ((row_in & 7) << 4);
      long arow = bm + row_in;
      if (arow >= NSRC) arow = NSRC - 1;
      const char* ga = (const char*)A + ((size_t)arow * 256 + k0) * 2 + colb;
      GLD16(ga, (char*)As + rb * 128);
    }
    {
      int rb = w * 8;
      int row_in = rb + lrow;
      int colb = (lchunk * 16) ^ ((row_in & 7) << 4);
      const char* gb = (const char*)B + ((size_t)row_in * 256 + k0) * 2 + colb;
      GLD16(gb, (char*)Bs + rb * 128);
    }
    __syncthreads();
    #pragma unroll
    for (int kk = 0; kk < 2; ++kk) {
      bf16x8 af[2], bg[2];
      #pragma unroll
      for (int m = 0; m < 2; ++m) {
        int row = wm + m * 16 + (l & 15);
        int colb = (kk * 64 + ((l >> 4) * 16)) ^ ((row & 7) << 4);
        af[m] = *(const bf16x8*)((const char*)As + row * 128 + colb);
      }
      #pragma unroll
      for (int n = 0; n < 2; ++n) {
        int row = n * 16 + (l & 15);
        int colb = (kk * 64 + ((l >> 4) * 16)) ^ ((row & 7) << 4);
        bg[n] = *(const bf16x8*)((const char*)Bs + row * 128 + colb);
      }
      #pragma unroll
      for (int m = 0; m < 2; ++m)
        #pragma unroll
        for (int n = 0; n < 2; ++n)
          acc[m][n] = __builtin_amdgcn_mfma_f32_16x16x32_bf16(af[m], bg[n], acc[m][n], 0, 0, 0);
    }
    __syncthreads();
  }
  #pragma unroll
  for (int m = 0; m < 2; ++m) {
    #pragma unroll
    for (int j = 0; j < 4; ++j) {
      int row = bm + wm + m * 16 + (l >> 4) * 4 + j;
      if (row < NSRC) {
        #pragma unroll
        for (int n = 0; n < 2; ++n) {
          int col = n * 16 + (l & 15);
          outF[(size_t)row * 32 + col] = acc[m][n][j];
        }
      }
    }
  }
}

// ---------------- fused final GEMM (z = head), fp8 xagg A-side ----------------
__global__ __launch_bounds__(256) void gemmF_k(const unsigned* __restrict__ xaggQ,
                                               const u16* __restrict__ xb,
                                               const u16* __restrict__ WBL,
                                               const float* __restrict__ loop_b,
                                               float* __restrict__ out) {
  __shared__ u16 As[128 * 64];
  __shared__ u16 Bs[64 * 64];
  const int tid = threadIdx.x;
  const int w = tid >> 6, l = tid & 63;
  const int h = blockIdx.z;
  const int bm = blockIdx.y * 128;
  const int wm = w * 32;
  const char* A1 = (const char*)xaggQ + (size_t)h * NDST * 1024;  // fp8 rows, 1024 B
  const u16* Bh = WBL + (size_t)h * 64 * 1280;
  f32x4 acc[2][4] = {};
  const int lrow = l >> 3, lchunk = l & 7;

  for (int t = 0; t < 20; ++t) {
    const int k0 = t * 64;
    if (t < 16) {
      // reg-staged fp8 -> bf16 decode into swizzled LDS
      int row_in = tid >> 1, half = tid & 1;
      long arow = bm + row_in;
      if (arow >= NDST) arow = NDST - 1;
      const uint4* gsrc = (const uint4*)(A1 + (size_t)arow * 1024 + k0 + half * 32);
      uint4 qa = gsrc[0];            // 16 fp8
      uint4 qb = gsrc[1];            // 16 fp8
      uint4 c0 = dec8_bf16(qa.x, qa.y);
      uint4 c1 = dec8_bf16(qa.z, qa.w);
      uint4 c2 = dec8_bf16(qb.x, qb.y);
      uint4 c3 = dec8_bf16(qb.z, qb.w);
      char* rowp = (char*)As + row_in * 128;
      const int sw = (row_in & 7) << 4;
      *(uint4*)(rowp + ((half * 64 + 0) ^ sw))  = c0;
      *(uint4*)(rowp + ((half * 64 + 16) ^ sw)) = c1;
      *(uint4*)(rowp + ((half * 64 + 32) ^ sw)) = c2;
      *(uint4*)(rowp + ((half * 64 + 48) ^ sw)) = c3;
    } else {
      #pragma unroll
      for (int c = 0; c < 4; ++c) {
        int rb = (w * 4 + c) * 8;
        int row_in = rb + lrow;
        int colb = (lchunk * 16) ^ ((row_in & 7) << 4);
        long arow = bm + row_in;
        if (arow >= NDST) arow = NDST - 1;
        const char* ga = (const char*)xb + ((size_t)arow * 256 + (k0 - 1024)) * 2 + colb;
        GLD16(ga, (char*)As + rb * 128);
      }
    }
    #pragma unroll
    for (int c = 0; c < 2; ++c) {
      int rb = (w * 2 + c) * 8;
      int row_in = rb + lrow;
      int colb = (lchunk * 16) ^ ((row_in & 7) << 4);
      const char* gb = (const char*)Bh + ((size_t)row_in * 1280 + k0) * 2 + colb;
      GLD16(gb, (char*)Bs + rb * 128);
    }
    __syncthreads();
    #pragma unroll
    for (int kk = 0; kk < 2; ++kk) {
      bf16x8 af[2], bg[4];
      #pragma unroll
      for (int m = 0; m < 2; ++m) {
        int row = wm + m * 16 + (l & 15);
        int colb = (kk * 64 + ((l >> 4) * 16)) ^ ((row & 7) << 4);
        af[m] = *(const bf16x8*)((const char*)As + row * 128 + colb);
      }
      #pragma unroll
      for (int n = 0; n < 4; ++n) {
        int row = n * 16 + (l & 15);
        int colb = (kk * 64 + ((l >> 4) * 16)) ^ ((row & 7) << 4);
        bg[n] = *(const bf16x8*)((const char*)Bs + row * 128 + colb);
      }
      #pragma unroll
      for (int m = 0; m < 2; ++m)
        #pragma unroll
        for (int n = 0; n < 4; ++n)
          acc[m][n] = __builtin_amdgcn_mfma_f32_16x16x32_bf16(af[m], bg[n], acc[m][n], 0, 0, 0);
    }
    __syncthreads();
  }
  #pragma unroll
  for (int m = 0; m < 2; ++m) {
    #pragma unroll
    for (int j = 0; j < 4; ++j) {
      int row = bm + wm + m * 16 + (l >> 4) * 4 + j;
      if (row < NDST) {
        #pragma unroll
        for (int n = 0; n < 4; ++n) {
          int col = n * 16 + (l & 15);
          out[(size_t)row * 256 + h * 64 + col] =
              fmaxf(acc[m][n][j] + loop_b[h * 64 + col], 0.f);
        }
      }
    }
  }
}

// ---------------- fused softmax + per-head x-aggregation (fp8 gather) ----------------
// 256-thread blocks, 4 INDEPENDENT waves: wave r owns segment (r, d). NO barriers —
// sex is per-wave LDS (same-wave LDS write->read is ordered; avoids r9's barrier
// coupling while 4x-ing waves per workgroup slot -> higher occupancy than 1-wave blocks.
static __device__ __forceinline__ void edge_fma(float (&ac)[4][4], float4 a4, unsigned q) {
  float f[4];
  dec4(q, f);
  const float ah[4] = {a4.x, a4.y, a4.z, a4.w};
  #pragma unroll
  for (int h = 0; h < 4; ++h)
    #pragma unroll
    for (int c = 0; c < 4; ++c)
      ac[h][c] = fmaf(ah[h], f[c], ac[h][c]);
}

__global__ __launch_bounds__(256) void agg_k(const unsigned* __restrict__ xq,
                                             const int* __restrict__ offs,
                                             const int* __restrict__ perm,
                                             const float* __restrict__ elr,
                                             unsigned* __restrict__ xaggQ) {
  __shared__ float sex[4][EMAXC][4];  // [wave][edge][head] normalized alpha, 8 KB
  const int d = blockIdx.x;
  const int r = threadIdx.x >> 6;    // wave id = relation
  const int lane = threadIdx.x & 63;
  const int seg = r * NDST + d;
  const int beg = offs[seg], end = offs[seg + 1];
  const int n = end - beg;
  const float4 r4 = *(const float4*)(elr + (size_t)d * 32 + 16 + r * 4);

  // phase A: denominators + exp cache (wave-private; no barrier needed)
  float s0 = 0.f, s1 = 0.f, s2 = 0.f, s3 = 0.f;
  for (int e = lane; e < n; e += 64) {
    int s = perm[beg + e];
    float4 l4 = *(const float4*)(elr + (size_t)s * 32 + r * 4);
    float e0 = __expf(leaky(l4.x + r4.x));
    float e1 = __expf(leaky(l4.y + r4.y));
    float e2 = __expf(leaky(l4.z + r4.z));
    float e3 = __expf(leaky(l4.w + r4.w));
    if (e < EMAXC) *(float4*)&sex[r][e][0] = make_float4(e0, e1, e2, e3);
    s0 += e0; s1 += e1; s2 += e2; s3 += e3;
  }
  #pragma unroll
  for (int off = 1; off < 64; off <<= 1) {
    s0 += __shfl_xor(s0, off);
    s1 += __shfl_xor(s1, off);
    s2 += __shfl_xor(s2, off);
    s3 += __shfl_xor(s3, off);
  }
  const float rd0 = 1.f / fmaxf(s0, 1e-9f);
  const float rd1 = 1.f / fmaxf(s1, 1e-9f);
  const float rd2 = 1.f / fmaxf(s2, 1e-9f);
  const float rd3 = 1.f / fmaxf(s3, 1e-9f);
  for (int e = lane; e < n && e < EMAXC; e += 64) {
    float4 v = *(const float4*)&sex[r][e][0];
    *(float4*)&sex[r][e][0] = make_float4(v.x * rd0, v.y * rd1, v.z * rd2, v.w * rd3);
  }
  // no __syncthreads: cross-lane LDS visibility within a wave is in program order

  // phase B: lane owns channels [lane*4, lane*4+4); 4-edge unroll
  float ac[4][4] = {};  // [head][ch]
  const int nc = (n < EMAXC) ? n : EMAXC;
  int e = 0;
  for (; e + 3 < nc; e += 4) {
    int sA = perm[beg + e], sB = perm[beg + e + 1];
    int sC = perm[beg + e + 2], sD = perm[beg + e + 3];
    float4 aA = *(const float4*)&sex[r][e][0];
    float4 aB = *(const float4*)&sex[r][e + 1][0];
    float4 aC = *(const float4*)&sex[r][e + 2][0];
    float4 aD = *(const float4*)&sex[r][e + 3][0];
    unsigned qA = xq[(size_t)sA * 64 + lane];
    unsigned qB = xq[(size_t)sB * 64 + lane];
    unsigned qC = xq[(size_t)sC * 64 + lane];
    unsigned qD = xq[(size_t)sD * 64 + lane];
    edge_fma(ac, aA, qA);
    edge_fma(ac, aB, qB);
    edge_fma(ac, aC, qC);
    edge_fma(ac, aD, qD);
  }
  for (; e < nc; ++e) {
    int s = perm[beg + e];
    float4 aa = *(const float4*)&sex[r][e][0];
    unsigned q = xq[(size_t)s * 64 + lane];
    edge_fma(ac, aa, q);
  }
  // overflow path (degree > EMAXC; essentially never for this graph)
  for (int i = EMAXC; i < n; ++i) {
    int s = perm[beg + i];
    float4 l4 = *(const float4*)(elr + (size_t)s * 32 + r * 4);
    float4 aa;
    aa.x = __expf(leaky(l4.x + r4.x)) * rd0;
    aa.y = __expf(leaky(l4.y + r4.y)) * rd1;
    aa.z = __expf(leaky(l4.z + r4.z)) * rd2;
    aa.w = __expf(leaky(l4.w + r4.w)) * rd3;
    unsigned q = xq[(size_t)s * 64 + lane];
    edge_fma(ac, aa, q);
  }

  // direct fp8 write: xaggQ[h][d] row (1024 B), u32 at r*64 + lane
  #pragma unroll
  for (int h = 0; h < 4; ++h) {
    xaggQ[((size_t)h * NDST + d) * 256 + (size_t)r * 64 + lane] =
        enc4(ac[h][0], ac[h][1], ac[h][2], ac[h][3]);
  }
}

// ---------------- launcher ----------------
extern "C" void kernel_launch(void* const* d_in, const int* in_sizes, int n_in,
                              void* d_out, int out_size, void* d_ws, size_t ws_size,
                              hipStream_t stream) {
  const float* x      = (const float*)d_in[0];
  const float* W      = (const float*)d_in[1];
  const float* attn_l = (const float*)d_in[2];
  const float* attn_r = (const float*)d_in[3];
  const float* loop_w = (const float*)d_in[4];
  const float* loop_b = (const float*)d_in[5];
  const int* edge_src = (const int*)d_in[6];
  const int* edge_dst = (const int*)d_in[7];
  float* out = (float*)d_out;

  char* wsp = (char*)d_ws;
  size_t off = 0;
  auto alloc = [&](size_t bytes) -> char* {
    char* p = wsp + off;
    off = (off + bytes + 255) & ~(size_t)255;
    return p;
  };
  u16* xb        = (u16*)alloc((size_t)NSRC * 256 * 2);        // 25.6 MB
  unsigned* xq   = (unsigned*)alloc((size_t)NSRC * 64 * 4);    // 12.8 MB (fp8)
  u16* WBL       = (u16*)alloc((size_t)4 * 64 * 1280 * 2);     // 0.66 MB
  u16* WAt       = (u16*)alloc((size_t)128 * 256 * 2);         // 65 KB
  float* elr     = (float*)alloc((size_t)NSRC * 32 * 4);       // 6.4 MB
  unsigned* xaggQ= (unsigned*)alloc((size_t)4 * NDST * 256 * 4); // 41 MB (fp8)
  u16* ranks     = (u16*)alloc((size_t)NREL * NEDGE * 2);      // 2 MB
  unsigned* bh   = (unsigned*)alloc((size_t)NREL * NBLK * NDST * 4);  // 5.1 MB
  int* counts    = (int*)alloc((size_t)NSEG * 4);
  int* offs      = (int*)alloc((size_t)(NSEG + 1) * 4);
  int* btot      = (int*)alloc(64 * 4);
  int* carry     = (int*)alloc(64 * 4);
  int* perm      = (int*)alloc((size_t)NREL * NEDGE * 4);      // total ~98 MB

  // merged prep (8 items/thread): cvtx(+fp8) | WBL | WAt
  prep_k<<<CB_CVTX + CB_WBL + CB_WA, 256, 0, stream>>>(
      x, W, loop_w, attn_l, attn_r, xb, xq, WBL, WAt);

  // atomic-free CSR build
  histrank_k<<<dim3(NBLK, NREL), 256, 0, stream>>>(edge_dst, ranks, bh);
  scanbb_k<<<(NSEG + 255) / 256, 256, 0, stream>>>(bh, counts);
  scanA_k<<<40, 1024, 0, stream>>>(counts, offs, btot);
  scanB_k<<<1, 64, 0, stream>>>(btot, carry);
  scanC_k<<<40, 1024, 0, stream>>>(offs, carry);
  place_k<<<(NREL * NEDGE + 255) / 256, 256, 0, stream>>>(
      edge_src, edge_dst, ranks, bh, offs, perm);

  // elr skinny GEMM: elr[NSRC][32] f32 (N=32 tile)
  gemmE_k<<<dim3(1, (NSRC + 127) / 128), 256, 0, stream>>>(xb, WAt, elr);

  // fused softmax + per-head x-aggregation (fp8 gather) -> xaggQ (fp8)
  agg_k<<<NDST, 256, 0, stream>>>(xq, offs, perm, elr, xaggQ);

  // fused final: out = relu([xagg_h(fp8) | xb(bf16)] @ WBL_h^T + loop_b), z = head
  gemmF_k<<<dim3(1, (NDST + 127) / 128, 4), 256, 0, stream>>>(
      xaggQ, xb, WBL, loop_b, out);
}

// Round 15
// 159.850 us; speedup vs baseline: 1.0868x; 1.0868x over previous
//
#include <hip/hip_runtime.h>

#define NSRC 50000
#define NDST 10000
#define NEDGE 250000
#define NREL 4
#define NEG_SLOPE 0.2f
#define EMAXC 128  // cached alphas per (d,r) segment; degree Binomial(250k,1e-4), max ~55
#define NSEG (NREL * NDST)
#define NBLK 32        // CSR-build blocks per relation
#define CHUNK 7813     // ceil(NEDGE / NBLK); fits u16 rank

typedef unsigned short u16;
typedef __attribute__((ext_vector_type(8))) short bf16x8;
typedef __attribute__((ext_vector_type(4))) float f32x4;
typedef __attribute__((ext_vector_type(2))) float f32x2;

#define GLD16(g, l) __builtin_amdgcn_global_load_lds( \
    (__attribute__((address_space(1))) void*)(void*)(g), \
    (__attribute__((address_space(3))) void*)(l), 16, 0, 0)

static __device__ __forceinline__ u16 f2b(float f) {
  unsigned u = __float_as_uint(f);
  unsigned r = (u + 0x7FFFu + ((u >> 16) & 1u)) >> 16;
  return (u16)r;
}
static __device__ __forceinline__ float b2f(u16 b) {
  return __uint_as_float((unsigned)b << 16);
}
static __device__ __forceinline__ float leaky(float x) {
  return x > 0.f ? x : NEG_SLOPE * x;
}

// ---------- fp8 e4m3 (OCP) helpers ----------
static __device__ __forceinline__ unsigned enc8_sw(float f) {
  unsigned s = (__float_as_uint(f) >> 24) & 0x80u;
  float a = fminf(fabsf(f), 448.f);
  unsigned em;
  if (a < 0x1p-6f) {
    em = (unsigned)rintf(a * 512.f);  // subnormal (and exact 2^-6 boundary)
  } else {
    unsigned ab = __float_as_uint(a);
    unsigned lsb = (ab >> 20) & 1u;
    ab += 0x7FFFFu + lsb;             // RNE to 3 mantissa bits
    int e = (int)(ab >> 23) - 127;
    unsigned m = (ab >> 20) & 7u;
    em = (unsigned)((e + 7) << 3) | m;
    if (em > 0x7Eu) em = 0x7Eu;       // clamp to 448
  }
  return s | em;
}
static __device__ __forceinline__ float dec8_sw(unsigned b) {
  unsigned s = b & 0x80u;
  unsigned em = b & 0x7Fu;
  float n = __uint_as_float((s << 24) | ((em << 20) + 0x3C000000u));
  float sub = (s ? -1.f : 1.f) * (float)em * 0x1p-9f;
  return em >= 8 ? n : sub;
}
static __device__ __forceinline__ unsigned enc4(float a, float b, float c, float d) {
#if __has_builtin(__builtin_amdgcn_cvt_pk_fp8_f32)
  int q = __builtin_amdgcn_cvt_pk_fp8_f32(a, b, 0, 0);
  q = __builtin_amdgcn_cvt_pk_fp8_f32(c, d, q, 1);
  return (unsigned)q;
#else
  return enc8_sw(a) | (enc8_sw(b) << 8) | (enc8_sw(c) << 16) | (enc8_sw(d) << 24);
#endif
}
static __device__ __forceinline__ void dec4(unsigned q, float f[4]) {
#if __has_builtin(__builtin_amdgcn_cvt_pk_f32_fp8)
  f32x2 lo = __builtin_amdgcn_cvt_pk_f32_fp8((int)q, 0);
  f32x2 hi = __builtin_amdgcn_cvt_pk_f32_fp8((int)q, 1);
  f[0] = lo.x; f[1] = lo.y; f[2] = hi.x; f[3] = hi.y;
#else
  f[0] = dec8_sw(q & 0xff); f[1] = dec8_sw((q >> 8) & 0xff);
  f[2] = dec8_sw((q >> 16) & 0xff); f[3] = dec8_sw(q >> 24);
#endif
}
// pack 2 f32 -> 1 u32 of 2 bf16 (exact here: inputs are fp8-valued)
static __device__ __forceinline__ unsigned pk_bf16(float a, float b) {
  unsigned r;
  asm("v_cvt_pk_bf16_f32 %0, %1, %2" : "=v"(r) : "v"(a), "v"(b));
  return r;
}
// 8 fp8 (2 u32) -> 8 bf16 (uint4)
static __device__ __forceinline__ uint4 dec8_bf16(unsigned q0, unsigned q1) {
  float f[8];
  dec4(q0, f);
  dec4(q1, f + 4);
  uint4 o;
  o.x = pk_bf16(f[0], f[1]);
  o.y = pk_bf16(f[2], f[3]);
  o.z = pk_bf16(f[4], f[5]);
  o.w = pk_bf16(f[6], f[7]);
  return o;
}

// ---------------- merged prep (no hist): cvtx(+fp8) | cvtwBL | wa ----------------
#define CB_CVTX 1563
#define CB_WBL  160
#define CB_WA   16
#define NGRP 3200000       // NSRC*256/4 float4-groups

__global__ __launch_bounds__(256) void prep_k(const float* __restrict__ x,
                                              const float* __restrict__ W,
                                              const float* __restrict__ loop_w,
                                              const float* __restrict__ al,
                                              const float* __restrict__ ar,
                                              u16* __restrict__ xb,
                                              unsigned* __restrict__ xq,
                                              u16* __restrict__ WBL,
                                              u16* __restrict__ WAt) {
  const int bi = blockIdx.x;
  const int tid = threadIdx.x;
  if (bi < CB_CVTX) {
    const int base = bi * 2048 + tid;
    float4 v[8];
    #pragma unroll
    for (int it = 0; it < 8; ++it) {
      int i = base + it * 256;
      if (i < NGRP) v[it] = ((const float4*)x)[i];
    }
    #pragma unroll
    for (int it = 0; it < 8; ++it) {
      int i = base + it * 256;
      if (i < NGRP) {
        uint2 o;
        o.x = (unsigned)f2b(v[it].x) | ((unsigned)f2b(v[it].y) << 16);
        o.y = (unsigned)f2b(v[it].z) | ((unsigned)f2b(v[it].w) << 16);
        ((uint2*)xb)[i] = o;
        xq[i] = enc4(v[it].x, v[it].y, v[it].z, v[it].w);
      }
    }
  } else if (bi < CB_CVTX + CB_WBL) {
    // WBL[h][n(64)][k'(1280)]: k'<1024 -> 0.25*W[k'>>8][k'&255][h*64+n]; else loop_w
    const int g0 = (bi - CB_CVTX) * 2048 + tid;
    float v[8];
    #pragma unroll
    for (int it = 0; it < 8; ++it) {
      int g = g0 + it * 256;  // g < 327680 always (exact fit)
      int h = g / 81920, rem = g - h * 81920;
      int np = rem / 1280, kp = rem - np * 1280;
      if (kp < 1024)
        v[it] = 0.25f * W[(size_t)(kp >> 8) * 65536 + (size_t)(kp & 255) * 256 + h * 64 + np];
      else
        v[it] = loop_w[(size_t)(kp - 1024) * 256 + h * 64 + np];
    }
    #pragma unroll
    for (int it = 0; it < 8; ++it) WBL[g0 + it * 256] = f2b(v[it]);
  } else {
    const int g0 = (bi - CB_CVTX - CB_WBL) * 2048 + tid;
    #pragma unroll
    for (int it = 0; it < 8; ++it) {
      int g = g0 + it * 256;  // g < 32768 always
      int c = g >> 8, k = g & 255;
      float acc = 0.f;
      if (c < 32) {
        int cc = c & 15;
        int r = cc >> 2, h = cc & 3;
        const float* vec = ((c < 16) ? al : ar) + r * 256 + h * 64;
        const float* wrow = W + (size_t)r * 65536 + (size_t)k * 256 + h * 64;
        #pragma unroll 8
        for (int j = 0; j < 64; ++j) acc += wrow[j] * vec[j];
      }
      WAt[(size_t)c * 256 + k] = f2b(acc);
    }
  }
}

// ---------------- atomic-free CSR build ----------------
__global__ __launch_bounds__(256) void histrank_k(const int* __restrict__ edst,
                                                  u16* __restrict__ ranks,
                                                  unsigned* __restrict__ bhist) {
  __shared__ unsigned lh[NDST];  // 40 KB
  const int bi = blockIdx.x, r = blockIdx.y;
  for (int i = threadIdx.x; i < NDST; i += 256) lh[i] = 0;
  __syncthreads();
  const int base = bi * CHUNK;
  const int lim = (NEDGE - base < CHUNK) ? (NEDGE - base) : CHUNK;
  const int* ed = edst + (size_t)r * NEDGE + base;
  u16* rk = ranks + (size_t)r * NEDGE + base;
  for (int i = threadIdx.x; i < lim; i += 256) {
    int d = ed[i];
    rk[i] = (u16)atomicAdd(&lh[d], 1u);
  }
  __syncthreads();
  unsigned* bh = bhist + ((size_t)r * NBLK + bi) * NDST;
  for (int i = threadIdx.x; i < NDST; i += 256) bh[i] = lh[i];
}

__global__ __launch_bounds__(256) void scanbb_k(unsigned* __restrict__ bhist,
                                                int* __restrict__ counts) {
  int gid = blockIdx.x * 256 + threadIdx.x;
  if (gid >= NSEG) return;
  int r = gid / NDST, bin = gid - r * NDST;
  unsigned run = 0;
  unsigned* base = bhist + (size_t)r * NBLK * NDST + bin;
  #pragma unroll
  for (int b = 0; b < NBLK; ++b) {
    unsigned v = base[(size_t)b * NDST];
    base[(size_t)b * NDST] = run;
    run += v;
  }
  counts[gid] = (int)run;
}

__global__ void place_k(const int* __restrict__ esrc, const int* __restrict__ edst,
                        const u16* __restrict__ ranks,
                        const unsigned* __restrict__ bhist,
                        const int* __restrict__ offs, int* __restrict__ perm) {
  int g = blockIdx.x * 256 + threadIdx.x;
  if (g >= NREL * NEDGE) return;
  int r = g / NEDGE, e = g - r * NEDGE;
  int bi = e / CHUNK;
  int d = edst[g];
  int pos = offs[r * NDST + d] +
            (int)bhist[((size_t)r * NBLK + bi) * NDST + d] + (int)ranks[g];
  perm[pos] = esrc[g];
}

// ---------------- seg-offset scans (coalesced, 3 kernels) ----------------
__global__ __launch_bounds__(1024) void scanA_k(const int* __restrict__ counts,
                                                int* __restrict__ offsets,
                                                int* __restrict__ btot) {
  __shared__ int wsum[16];
  int tid = threadIdx.x, lane = tid & 63, wid = tid >> 6;
  int i = blockIdx.x * 1024 + tid;
  int v = (i < NSEG) ? counts[i] : 0;
  int x = v;
  #pragma unroll
  for (int off = 1; off < 64; off <<= 1) {
    int t = __shfl_up(x, off);
    if (lane >= off) x += t;
  }
  if (lane == 63) wsum[wid] = x;
  __syncthreads();
  if (wid == 0) {
    int t = (lane < 16) ? wsum[lane] : 0;
    #pragma unroll
    for (int off = 1; off < 16; off <<= 1) {
      int u = __shfl_up(t, off);
      if (lane >= off) t += u;
    }
    if (lane < 16) wsum[lane] = t;
  }
  __syncthreads();
  int wpre = (wid > 0) ? wsum[wid - 1] : 0;
  int incl = x + wpre;
  if (i < NSEG) offsets[i] = incl - v;
  if (tid == 1023) btot[blockIdx.x] = incl;
}

__global__ void scanB_k(const int* __restrict__ btot, int* __restrict__ carry) {
  int lane = threadIdx.x;  // 64 threads = 1 wave
  int v = (lane < 40) ? btot[lane] : 0;
  int x = v;
  #pragma unroll
  for (int off = 1; off < 64; off <<= 1) {
    int t = __shfl_up(x, off);
    if (lane >= off) x += t;
  }
  if (lane < 40) carry[lane] = x - v;
}

__global__ __launch_bounds__(1024) void scanC_k(int* __restrict__ offsets,
                                                const int* __restrict__ carry) {
  int i = blockIdx.x * 1024 + threadIdx.x;
  if (i < NSEG) offsets[i] += carry[blockIdx.x];
  if (i == 0) offsets[NSEG] = NREL * NEDGE;
}

// ---------------- elr GEMM: elr[NSRC][32] = xb @ WAt^T (N=32 tile) ----------------
__global__ __launch_bounds__(256) void gemmE_k(const u16* __restrict__ A,
                                               const u16* __restrict__ B,
                                               float* __restrict__ outF) {
  __shared__ u16 As[128 * 64];
  __shared__ u16 Bs[32 * 64];
  const int tid = threadIdx.x;
  const int w = tid >> 6, l = tid & 63;
  const int bm = blockIdx.y * 128;
  const int wm = w * 32;
  f32x4 acc[2][2] = {};
  const int lrow = l >> 3, lchunk = l & 7;

  for (int t = 0; t < 4; ++t) {
    const int k0 = t * 64;
    #pragma unroll
    for (int c = 0; c < 4; ++c) {
      int rb = (w * 4 + c) * 8;
      int row_in = rb + lrow;
      int colb = (lchunk * 16) ^ ((row_in & 7) << 4);
      long arow = bm + row_in;
      if (arow >= NSRC) arow = NSRC - 1;
      const char* ga = (const char*)A + ((size_t)arow * 256 + k0) * 2 + colb;
      GLD16(ga, (char*)As + rb * 128);
    }
    {
      int rb = w * 8;
      int row_in = rb + lrow;
      int colb = (lchunk * 16) ^ ((row_in & 7) << 4);
      const char* gb = (const char*)B + ((size_t)row_in * 256 + k0) * 2 + colb;
      GLD16(gb, (char*)Bs + rb * 128);
    }
    __syncthreads();
    #pragma unroll
    for (int kk = 0; kk < 2; ++kk) {
      bf16x8 af[2], bg[2];
      #pragma unroll
      for (int m = 0; m < 2; ++m) {
        int row = wm + m * 16 + (l & 15);
        int colb = (kk * 64 + ((l >> 4) * 16)) ^ ((row & 7) << 4);
        af[m] = *(const bf16x8*)((const char*)As + row * 128 + colb);
      }
      #pragma unroll
      for (int n = 0; n < 2; ++n) {
        int row = n * 16 + (l & 15);
        int colb = (kk * 64 + ((l >> 4) * 16)) ^ ((row & 7) << 4);
        bg[n] = *(const bf16x8*)((const char*)Bs + row * 128 + colb);
      }
      #pragma unroll
      for (int m = 0; m < 2; ++m)
        #pragma unroll
        for (int n = 0; n < 2; ++n)
          acc[m][n] = __builtin_amdgcn_mfma_f32_16x16x32_bf16(af[m], bg[n], acc[m][n], 0, 0, 0);
    }
    __syncthreads();
  }
  #pragma unroll
  for (int m = 0; m < 2; ++m) {
    #pragma unroll
    for (int j = 0; j < 4; ++j) {
      int row = bm + wm + m * 16 + (l >> 4) * 4 + j;
      if (row < NSRC) {
        #pragma unroll
        for (int n = 0; n < 2; ++n) {
          int col = n * 16 + (l & 15);
          outF[(size_t)row * 32 + col] = acc[m][n][j];
        }
      }
    }
  }
}

// ---------------- fused final GEMM (z = head), fp8 xagg A-side ----------------
__global__ __launch_bounds__(256) void gemmF_k(const unsigned* __restrict__ xaggQ,
                                               const u16* __restrict__ xb,
                                               const u16* __restrict__ WBL,
                                               const float* __restrict__ loop_b,
                                               float* __restrict__ out) {
  __shared__ u16 As[128 * 64];
  __shared__ u16 Bs[64 * 64];
  const int tid = threadIdx.x;
  const int w = tid >> 6, l = tid & 63;
  const int h = blockIdx.z;
  const int bm = blockIdx.y * 128;
  const int wm = w * 32;
  const char* A1 = (const char*)xaggQ + (size_t)h * NDST * 1024;  // fp8 rows, 1024 B
  const u16* Bh = WBL + (size_t)h * 64 * 1280;
  f32x4 acc[2][4] = {};
  const int lrow = l >> 3, lchunk = l & 7;

  for (int t = 0; t < 20; ++t) {
    const int k0 = t * 64;
    if (t < 16) {
      // reg-staged fp8 -> bf16 decode into swizzled LDS
      int row_in = tid >> 1, half = tid & 1;
      long arow = bm + row_in;
      if (arow >= NDST) arow = NDST - 1;
      const uint4* gsrc = (const uint4*)(A1 + (size_t)arow * 1024 + k0 + half * 32);
      uint4 qa = gsrc[0];            // 16 fp8
      uint4 qb = gsrc[1];            // 16 fp8
      uint4 c0 = dec8_bf16(qa.x, qa.y);
      uint4 c1 = dec8_bf16(qa.z, qa.w);
      uint4 c2 = dec8_bf16(qb.x, qb.y);
      uint4 c3 = dec8_bf16(qb.z, qb.w);
      char* rowp = (char*)As + row_in * 128;
      const int sw = (row_in & 7) << 4;
      *(uint4*)(rowp + ((half * 64 + 0) ^ sw))  = c0;
      *(uint4*)(rowp + ((half * 64 + 16) ^ sw)) = c1;
      *(uint4*)(rowp + ((half * 64 + 32) ^ sw)) = c2;
      *(uint4*)(rowp + ((half * 64 + 48) ^ sw)) = c3;
    } else {
      #pragma unroll
      for (int c = 0; c < 4; ++c) {
        int rb = (w * 4 + c) * 8;
        int row_in = rb + lrow;
        int colb = (lchunk * 16) ^ ((row_in & 7) << 4);
        long arow = bm + row_in;
        if (arow >= NDST) arow = NDST - 1;
        const char* ga = (const char*)xb + ((size_t)arow * 256 + (k0 - 1024)) * 2 + colb;
        GLD16(ga, (char*)As + rb * 128);
      }
    }
    #pragma unroll
    for (int c = 0; c < 2; ++c) {
      int rb = (w * 2 + c) * 8;
      int row_in = rb + lrow;
      int colb = (lchunk * 16) ^ ((row_in & 7) << 4);
      const char* gb = (const char*)Bh + ((size_t)row_in * 1280 + k0) * 2 + colb;
      GLD16(gb, (char*)Bs + rb * 128);
    }
    __syncthreads();
    #pragma unroll
    for (int kk = 0; kk < 2; ++kk) {
      bf16x8 af[2], bg[4];
      #pragma unroll
      for (int m = 0; m < 2; ++m) {
        int row = wm + m * 16 + (l & 15);
        int colb = (kk * 64 + ((l >> 4) * 16)) ^ ((row & 7) << 4);
        af[m] = *(const bf16x8*)((const char*)As + row * 128 + colb);
      }
      #pragma unroll
      for (int n = 0; n < 4; ++n) {
        int row = n * 16 + (l & 15);
        int colb = (kk * 64 + ((l >> 4) * 16)) ^ ((row & 7) << 4);
        bg[n] = *(const bf16x8*)((const char*)Bs + row * 128 + colb);
      }
      #pragma unroll
      for (int m = 0; m < 2; ++m)
        #pragma unroll
        for (int n = 0; n < 4; ++n)
          acc[m][n] = __builtin_amdgcn_mfma_f32_16x16x32_bf16(af[m], bg[n], acc[m][n], 0, 0, 0);
    }
    __syncthreads();
  }
  #pragma unroll
  for (int m = 0; m < 2; ++m) {
    #pragma unroll
    for (int j = 0; j < 4; ++j) {
      int row = bm + wm + m * 16 + (l >> 4) * 4 + j;
      if (row < NDST) {
        #pragma unroll
        for (int n = 0; n < 4; ++n) {
          int col = n * 16 + (l & 15);
          out[(size_t)row * 256 + h * 64 + col] =
              fmaxf(acc[m][n][j] + loop_b[h * 64 + col], 0.f);
        }
      }
    }
  }
}

// ---------------- fused softmax + per-head x-aggregation (fp8 gather) ----------------
// ONE WAVE per (d,r) segment: grid (NDST, NREL), block 64. Wave-granular
// scheduling absorbs Poisson degree imbalance (r9/r14 showed multi-wave
// packing recouples the tail). Output fp8.
static __device__ __forceinline__ void edge_fma(float (&ac)[4][4], float4 a4, unsigned q) {
  float f[4];
  dec4(q, f);
  const float ah[4] = {a4.x, a4.y, a4.z, a4.w};
  #pragma unroll
  for (int h = 0; h < 4; ++h)
    #pragma unroll
    for (int c = 0; c < 4; ++c)
      ac[h][c] = fmaf(ah[h], f[c], ac[h][c]);
}

__global__ __launch_bounds__(64) void agg_k(const unsigned* __restrict__ xq,
                                            const int* __restrict__ offs,
                                            const int* __restrict__ perm,
                                            const float* __restrict__ elr,
                                            unsigned* __restrict__ xaggQ) {
  __shared__ float sex[EMAXC][4];  // [edge][head] normalized alpha
  const int d = blockIdx.x;
  const int r = blockIdx.y;
  const int lane = threadIdx.x;
  const int seg = r * NDST + d;
  const int beg = offs[seg], end = offs[seg + 1];
  const int n = end - beg;
  const float4 r4 = *(const float4*)(elr + (size_t)d * 32 + 16 + r * 4);

  // phase A: denominators + exp cache
  float s0 = 0.f, s1 = 0.f, s2 = 0.f, s3 = 0.f;
  for (int e = lane; e < n; e += 64) {
    int s = perm[beg + e];
    float4 l4 = *(const float4*)(elr + (size_t)s * 32 + r * 4);
    float e0 = __expf(leaky(l4.x + r4.x));
    float e1 = __expf(leaky(l4.y + r4.y));
    float e2 = __expf(leaky(l4.z + r4.z));
    float e3 = __expf(leaky(l4.w + r4.w));
    if (e < EMAXC) *(float4*)&sex[e][0] = make_float4(e0, e1, e2, e3);
    s0 += e0; s1 += e1; s2 += e2; s3 += e3;
  }
  #pragma unroll
  for (int off = 1; off < 64; off <<= 1) {
    s0 += __shfl_xor(s0, off);
    s1 += __shfl_xor(s1, off);
    s2 += __shfl_xor(s2, off);
    s3 += __shfl_xor(s3, off);
  }
  const float rd0 = 1.f / fmaxf(s0, 1e-9f);
  const float rd1 = 1.f / fmaxf(s1, 1e-9f);
  const float rd2 = 1.f / fmaxf(s2, 1e-9f);
  const float rd3 = 1.f / fmaxf(s3, 1e-9f);
  for (int e = lane; e < n && e < EMAXC; e += 64) {
    float4 v = *(const float4*)&sex[e][0];
    *(float4*)&sex[e][0] = make_float4(v.x * rd0, v.y * rd1, v.z * rd2, v.w * rd3);
  }
  __syncthreads();

  // phase B: lane owns channels [lane*4, lane*4+4); 4-edge unroll
  float ac[4][4] = {};  // [head][ch]
  const int nc = (n < EMAXC) ? n : EMAXC;
  int e = 0;
  for (; e + 3 < nc; e += 4) {
    int sA = perm[beg + e], sB = perm[beg + e + 1];
    int sC = perm[beg + e + 2], sD = perm[beg + e + 3];
    float4 aA = *(const float4*)&sex[e][0];
    float4 aB = *(const float4*)&sex[e + 1][0];
    float4 aC = *(const float4*)&sex[e + 2][0];
    float4 aD = *(const float4*)&sex[e + 3][0];
    unsigned qA = xq[(size_t)sA * 64 + lane];
    unsigned qB = xq[(size_t)sB * 64 + lane];
    unsigned qC = xq[(size_t)sC * 64 + lane];
    unsigned qD = xq[(size_t)sD * 64 + lane];
    edge_fma(ac, aA, qA);
    edge_fma(ac, aB, qB);
    edge_fma(ac, aC, qC);
    edge_fma(ac, aD, qD);
  }
  for (; e < nc; ++e) {
    int s = perm[beg + e];
    float4 aa = *(const float4*)&sex[e][0];
    unsigned q = xq[(size_t)s * 64 + lane];
    edge_fma(ac, aa, q);
  }
  // overflow path (degree > EMAXC; essentially never for this graph)
  for (int i = EMAXC; i < n; ++i) {
    int s = perm[beg + i];
    float4 l4 = *(const float4*)(elr + (size_t)s * 32 + r * 4);
    float4 aa;
    aa.x = __expf(leaky(l4.x + r4.x)) * rd0;
    aa.y = __expf(leaky(l4.y + r4.y)) * rd1;
    aa.z = __expf(leaky(l4.z + r4.z)) * rd2;
    aa.w = __expf(leaky(l4.w + r4.w)) * rd3;
    unsigned q = xq[(size_t)s * 64 + lane];
    edge_fma(ac, aa, q);
  }

  // direct fp8 write: xaggQ[h][d] row (1024 B), u32 at r*64 + lane
  #pragma unroll
  for (int h = 0; h < 4; ++h) {
    xaggQ[((size_t)h * NDST + d) * 256 + (size_t)r * 64 + lane] =
        enc4(ac[h][0], ac[h][1], ac[h][2], ac[h][3]);
  }
}

// ---------------- launcher ----------------
extern "C" void kernel_launch(void* const* d_in, const int* in_sizes, int n_in,
                              void* d_out, int out_size, void* d_ws, size_t ws_size,
                              hipStream_t stream) {
  const float* x      = (const float*)d_in[0];
  const float* W      = (const float*)d_in[1];
  const float* attn_l = (const float*)d_in[2];
  const float* attn_r = (const float*)d_in[3];
  const float* loop_w = (const float*)d_in[4];
  const float* loop_b = (const float*)d_in[5];
  const int* edge_src = (const int*)d_in[6];
  const int* edge_dst = (const int*)d_in[7];
  float* out = (float*)d_out;

  char* wsp = (char*)d_ws;
  size_t off = 0;
  auto alloc = [&](size_t bytes) -> char* {
    char* p = wsp + off;
    off = (off + bytes + 255) & ~(size_t)255;
    return p;
  };
  u16* xb        = (u16*)alloc((size_t)NSRC * 256 * 2);        // 25.6 MB
  unsigned* xq   = (unsigned*)alloc((size_t)NSRC * 64 * 4);    // 12.8 MB (fp8)
  u16* WBL       = (u16*)alloc((size_t)4 * 64 * 1280 * 2);     // 0.66 MB
  u16* WAt       = (u16*)alloc((size_t)128 * 256 * 2);         // 65 KB
  float* elr     = (float*)alloc((size_t)NSRC * 32 * 4);       // 6.4 MB
  unsigned* xaggQ= (unsigned*)alloc((size_t)4 * NDST * 256 * 4); // 41 MB (fp8)
  u16* ranks     = (u16*)alloc((size_t)NREL * NEDGE * 2);      // 2 MB
  unsigned* bh   = (unsigned*)alloc((size_t)NREL * NBLK * NDST * 4);  // 5.1 MB
  int* counts    = (int*)alloc((size_t)NSEG * 4);
  int* offs      = (int*)alloc((size_t)(NSEG + 1) * 4);
  int* btot      = (int*)alloc(64 * 4);
  int* carry     = (int*)alloc(64 * 4);
  int* perm      = (int*)alloc((size_t)NREL * NEDGE * 4);      // total ~98 MB

  // merged prep (8 items/thread): cvtx(+fp8) | WBL | WAt
  prep_k<<<CB_CVTX + CB_WBL + CB_WA, 256, 0, stream>>>(
      x, W, loop_w, attn_l, attn_r, xb, xq, WBL, WAt);

  // atomic-free CSR build
  histrank_k<<<dim3(NBLK, NREL), 256, 0, stream>>>(edge_dst, ranks, bh);
  scanbb_k<<<(NSEG + 255) / 256, 256, 0, stream>>>(bh, counts);
  scanA_k<<<40, 1024, 0, stream>>>(counts, offs, btot);
  scanB_k<<<1, 64, 0, stream>>>(btot, carry);
  scanC_k<<<40, 1024, 0, stream>>>(offs, carry);
  place_k<<<(NREL * NEDGE + 255) / 256, 256, 0, stream>>>(
      edge_src, edge_dst, ranks, bh, offs, perm);

  // elr skinny GEMM: elr[NSRC][32] f32 (N=32 tile)
  gemmE_k<<<dim3(1, (NSRC + 127) / 128), 256, 0, stream>>>(xb, WAt, elr);

  // fused softmax + per-head x-aggregation (fp8 gather) -> xaggQ (fp8)
  agg_k<<<dim3(NDST, NREL), 64, 0, stream>>>(xq, offs, perm, elr, xaggQ);

  // fused final: out = relu([xagg_h(fp8) | xb(bf16)] @ WBL_h^T + loop_b), z = head
  gemmF_k<<<dim3(1, (NDST + 127) / 128, 4), 256, 0, stream>>>(
      xaggQ, xb, WBL, loop_b, out);
}